// Round 16
// baseline (153.770 us; speedup 1.0000x reference)
//
#include <hip/hip_runtime.h>
#include <hip/hip_bf16.h>
#include <math.h>

// GNO collapsed: h = lift(x); per layer h = gelu(h@weff + beff),
//   weff = Wb + c0*(A@T' + qk su^T),  beff = bb + c0*(kq.T' + qbk su),
//   A = Wq@Wk^T, qk = Wq@bk, kq = Wk@bq, qbk = bq.bk     (G-INDEPENDENT)
//   T' = G@Wv + s bv^T,  su = Wv^T s + N bv,  G = h^T h, s = h^T 1.
// Round 28 = r27 (150.6us) + E moved BEFORE D: the A=Wq@Wk^T shadow matmul
// now runs inside the combine blocks' ~7us aflag poll window (E needs only
// C's staging, is G-independent). Previously E sat AFTER D on the combine
// blocks' serial chain, and their lateness propagated into every next
// layer's aflag round. Order: A -> aflag -> C -> sync -> E -> sync -> D
// (combine) -> Wb stage -> F -> H -> apply. Everything else r27-verbatim
// (direct permuted partial stores, combine computes T'+su, 2 rounds/layer).
// Session: 157.3 -> 154.2 (T' in combine) -> 152.3 (su in combine) ->
// 150.6 (direct stores). Decision rule: bench >= 151us -> revert r27.

#define NLAYER 4
#define NB 2
#define NN 4096
#define DD 64
#define RPB 32              // rows per block (8192 rows / 256 blocks)
#define NT 256
#define NBLK 256
#define SHP 68              // padded LDS row stride (floats)
#define C0F (1.0f/32768.0f)
#define PSZ 4160            // partial floats: full G 4096 (permuted rows) + s 64
#define GSZ 4224            // published floats: T'raw 4096 + s 64 + su 64
#define NCH 128             // producers per batch

typedef __hip_bfloat16 bf16;
typedef unsigned long long u64t;

__device__ __forceinline__ float b2f(const bf16 v) { return __bfloat162float(v); }

template <typename T> struct Acc;
template <> struct Acc<float> {
    static __device__ __forceinline__ float ld(const void* p, int i) { return ((const float*)p)[i]; }
    static __device__ __forceinline__ void st(void* p, int i, float v) { ((float*)p)[i] = v; }
};
template <> struct Acc<bf16> {
    static __device__ __forceinline__ float ld(const void* p, int i) { return b2f(((const bf16*)p)[i]); }
    static __device__ __forceinline__ void st(void* p, int i, float v) { ((bf16*)p)[i] = __float2bfloat16(v); }
};

__device__ __forceinline__ float gelu_exact(float x) {
    return 0.5f * x * (1.0f + erff(x * 0.70710678118654752f));
}

// ---- device-coherent helpers (agent scope, relaxed) ----
__device__ __forceinline__ float2 ldc2(const float* p) {
    u64t v = __hip_atomic_load((const u64t*)p, __ATOMIC_RELAXED, __HIP_MEMORY_SCOPE_AGENT);
    float2 r;
    r.x = __uint_as_float((unsigned)v);
    r.y = __uint_as_float((unsigned)(v >> 32));
    return r;
}
__device__ __forceinline__ void stc(float* p, float v) {
    __hip_atomic_store((unsigned*)p, __float_as_uint(v), __ATOMIC_RELAXED, __HIP_MEMORY_SCOPE_AGENT);
}
__device__ __forceinline__ void stc2(float* p, float a, float b) {
    u64t v = ((u64t)__float_as_uint(b) << 32) | (u64t)__float_as_uint(a);
    __hip_atomic_store((u64t*)p, v, __ATOMIC_RELAXED, __HIP_MEMORY_SCOPE_AGENT);
}
__device__ __forceinline__ unsigned ldw(unsigned* p) {
    return __hip_atomic_load(p, __ATOMIC_RELAXED, __HIP_MEMORY_SCOPE_AGENT);
}
__device__ __forceinline__ void stw(unsigned* p, unsigned v) {
    __hip_atomic_store(p, v, __ATOMIC_RELAXED, __HIP_MEMORY_SCOPE_AGENT);
}
__device__ __forceinline__ void pollw(unsigned* p, unsigned ep) {
    int guard = 0;
    while (ldw(p) < ep && ++guard < (1 << 18)) __builtin_amdgcn_s_sleep(2);
}

// acc[a][b] += sum_k L[a].k * R[k].b   (NN product step)
__device__ __forceinline__ void mm4x4(float (&acc)[4][4],
    float4 L0, float4 L1, float4 L2, float4 L3,
    float4 R0, float4 R1, float4 R2, float4 R3)
{
    const float L[4][4] = {{L0.x,L0.y,L0.z,L0.w},{L1.x,L1.y,L1.z,L1.w},
                           {L2.x,L2.y,L2.z,L2.w},{L3.x,L3.y,L3.z,L3.w}};
    const float R[4][4] = {{R0.x,R0.y,R0.z,R0.w},{R1.x,R1.y,R1.z,R1.w},
                           {R2.x,R2.y,R2.z,R2.w},{R3.x,R3.y,R3.z,R3.w}};
    #pragma unroll
    for (int a = 0; a < 4; a++)
        #pragma unroll
        for (int k = 0; k < 4; k++)
            #pragma unroll
            for (int b = 0; b < 4; b++)
                acc[a][b] += L[a][k] * R[k][b];
}

// acc[a][b] += sum_k L[a].k * R[b].k   (NT product step: A = Wq @ Wk^T)
__device__ __forceinline__ void mmNT4x4(float (&acc)[4][4],
    float4 L0, float4 L1, float4 L2, float4 L3,
    float4 R0, float4 R1, float4 R2, float4 R3)
{
    const float L[4][4] = {{L0.x,L0.y,L0.z,L0.w},{L1.x,L1.y,L1.z,L1.w},
                           {L2.x,L2.y,L2.z,L2.w},{L3.x,L3.y,L3.z,L3.w}};
    const float R[4][4] = {{R0.x,R0.y,R0.z,R0.w},{R1.x,R1.y,R1.z,R1.w},
                           {R2.x,R2.y,R2.z,R2.w},{R3.x,R3.y,R3.z,R3.w}};
    #pragma unroll
    for (int a = 0; a < 4; a++)
        #pragma unroll
        for (int b = 0; b < 4; b++)
            #pragma unroll
            for (int k = 0; k < 4; k++)
                acc[a][b] += L[a][k] * R[b][k];
}

// acc[a][b] += A.a * B.b
__device__ __forceinline__ void outer4x4(float (&acc)[4][4], float4 A, float4 B)
{
    const float Aa[4] = {A.x, A.y, A.z, A.w};
    const float Ba[4] = {B.x, B.y, B.z, B.w};
    #pragma unroll
    for (int a = 0; a < 4; a++)
        #pragma unroll
        for (int b = 0; b < 4; b++)
            acc[a][b] += Aa[a] * Ba[b];
}

// LDS layout (floats):
//   sH  [32][68]  @ 0      resident h rows
//   B1  [64][68]  @ 2176   Wq
//   B2  [64][68]  @ 6528   A (shadow-computed, persists through weff)
//   B3  [64][68]  @ 10880  combine scratch RED; then T'
//   B4  [64][68]  @ 15232  Wk -> Wb
//   B5  [64][68]  @ 19584  Wv -> weff
//   smalls @ 23936..24511 ; red [4][64] @ 24512
// total 24768 floats = 99072 B -> 1 block/CU, 256 blocks co-resident.

#define SM_SS   23936
#define SM_SU   24000
#define SM_BK   24064
#define SM_BQ   24128
#define SM_BV   24192
#define SM_BE   24256
#define SM_QK   24320
#define SM_KQ   24384
#define SM_QBK  24448
#define SM_RED  24512
#define SM_TOT  24768

template <typename T>
__device__ void run_net(
    const void* x, const void* lw, const void* lb,
    const void* blkw, const void* blkb,
    const void* qw, const void* qb, const void* kw, const void* kb,
    const void* vw, const void* vb, const void* pw, const void* pb,
    void* out, float* Gpart, float* Gg,
    unsigned* aflag, unsigned* cflag,
    float* smem, int blk, int t)
{
    float (*sH)[SHP] = (float(*)[SHP])(smem);
    float (*B1)[SHP] = (float(*)[SHP])(smem + 2176);
    float (*B2)[SHP] = (float(*)[SHP])(smem + 6528);
    float (*B3)[SHP] = (float(*)[SHP])(smem + 10880);
    float (*B4)[SHP] = (float(*)[SHP])(smem + 15232);
    float (*B5)[SHP] = (float(*)[SHP])(smem + 19584);
    float* RED = smem + 10880;          // combine scratch (aliases B3)
    float* suS = smem + SM_SU;
    float* bkS = smem + SM_BK;
    float* bqS = smem + SM_BQ;
    float* bvS = smem + SM_BV;
    float* beS = smem + SM_BE;
    float* qkS = smem + SM_QK;
    float* kqS = smem + SM_KQ;
    float* qbkS = smem + SM_QBK;
    float (*red)[DD] = (float(*)[DD])(smem + SM_RED);

    const int row0 = blk * RPB;
    const int bb = blk >> 7;                      // batch of this block
    const int RC = blk & 127;                     // combine role: rows 0..63, s/su=64
    const int r = t >> 4, c4 = (t & 15) << 2;     // apply/lift mapping
    const int i4 = t >> 4, j4 = t & 15;           // 4x4 tile grid coords
    const int r0 = i4 << 2, c0 = j4 << 2;

    // ---- lift: 32 rows of h into resident LDS ----
    #pragma unroll
    for (int a = 0; a < 2; a++) {
        const int row = r + 16 * a, gr = row0 + row;
        float x0 = Acc<T>::ld(x, gr * 3 + 0);
        float x1 = Acc<T>::ld(x, gr * 3 + 1);
        float x2 = Acc<T>::ld(x, gr * 3 + 2);
        float o[4];
        #pragma unroll
        for (int b = 0; b < 4; b++) {
            int c = c4 + b;
            o[b] = Acc<T>::ld(lb, c) + x0 * Acc<T>::ld(lw, c)
                 + x1 * Acc<T>::ld(lw, DD + c) + x2 * Acc<T>::ld(lw, 2 * DD + c);
        }
        *(float4*)&sH[row][c4] = make_float4(o[0], o[1], o[2], o[3]);
    }
    __syncthreads();

    for (int layer = 0; layer < NLAYER; layer++) {
        const unsigned ep = (unsigned)(layer + 1);
        float* GgL = Gg + (size_t)(layer * NB + bb) * GSZ;   // T'raw + s + su
        const int wOff = layer * DD * DD, bOff = layer * DD;

        // ---- A: G-partial computed and stored DIRECTLY (permuted rows) ----
        {
            float* slot = Gpart + (size_t)blk * PSZ;
            float m[4][4];
            #pragma unroll
            for (int a = 0; a < 4; a++)
                #pragma unroll
                for (int b = 0; b < 4; b++) m[a][b] = 0.f;
            #pragma unroll 8
            for (int n = 0; n < RPB; n++)
                outer4x4(m, *(const float4*)&sH[n][r0], *(const float4*)&sH[n][c0]);
            #pragma unroll
            for (int a = 0; a < 4; a++) {
                float* rowp = slot + (r0 + a) * DD;
                stc2(rowp + 2 * j4,      m[a][0], m[a][1]);
                stc2(rowp + 32 + 2 * j4, m[a][2], m[a][3]);
            }
            if (t < DD) {
                float ss = 0.f;
                #pragma unroll 8
                for (int n = 0; n < RPB; n++) ss += sH[n][t];
                stc(&slot[4096 + t], ss);   // natural order, contiguous 4B
            }
        }
        __syncthreads();                // vmcnt(0) per wave: partial fully visible
        if (t == 0) stw(&aflag[blk], ep);

        // ---- C: stage Wq->B1, Wk->B4, Wv->B5 + bias vectors ----
        for (int i2 = t; i2 < DD * DD; i2 += NT) {
            B1[i2 >> 6][i2 & 63] = Acc<T>::ld(qw, wOff + i2);
            B4[i2 >> 6][i2 & 63] = Acc<T>::ld(kw, wOff + i2);
            B5[i2 >> 6][i2 & 63] = Acc<T>::ld(vw, wOff + i2);
        }
        if (t < DD) {
            bkS[t] = Acc<T>::ld(kb, bOff + t);
            bqS[t] = Acc<T>::ld(qb, bOff + t);
            bvS[t] = Acc<T>::ld(vb, bOff + t);
        }
        __syncthreads();                // staging visible (E reads B1/B4/biases)

        // ---- E (pre-D: hides in combine blocks' aflag poll window):
        //      A = Wq@Wk^T, qk, kq, qbk ----
        {
            float acc[4][4];
            #pragma unroll
            for (int a = 0; a < 4; a++)
                #pragma unroll
                for (int b = 0; b < 4; b++) acc[a][b] = 0.f;
            #pragma unroll 2
            for (int e = 0; e < DD; e += 4)
                mmNT4x4(acc,
                      *(const float4*)&B1[r0 + 0][e], *(const float4*)&B1[r0 + 1][e],
                      *(const float4*)&B1[r0 + 2][e], *(const float4*)&B1[r0 + 3][e],
                      *(const float4*)&B4[c0 + 0][e], *(const float4*)&B4[c0 + 1][e],
                      *(const float4*)&B4[c0 + 2][e], *(const float4*)&B4[c0 + 3][e]);
            #pragma unroll
            for (int a = 0; a < 4; a++)
                *(float4*)&B2[r0 + a][c0] = make_float4(acc[a][0], acc[a][1], acc[a][2], acc[a][3]);

            if (t < DD) {               // qk = Wq@bk
                float u = 0.f;
                for (int e = 0; e < DD; e++) u += B1[t][e] * bkS[e];
                qkS[t] = u;
            } else if (t < 2 * DD) {    // kq = Wk@bq
                const int rr = t - DD;
                float u = 0.f;
                for (int e = 0; e < DD; e++) u += B4[rr][e] * bqS[e];
                kqS[rr] = u;
            } else if (t == 2 * DD) {   // qbk = bq.bk
                float u = 0.f;
                for (int e = 0; e < DD; e++) u += bqS[e] * bkS[e];
                qbkS[0] = u;
            }
        }
        __syncthreads();                // E done: B1/B4 free, qkS/kqS/qbkS visible

        // ---- D (combine roles only): reduce row RC across 128 slots;
        //      rows 0..63 compute T'raw[RC] = G[RC]@Wv; RC==64 -> s AND su ----
        if (RC <= 64) {
            if (t < NCH) pollw(&aflag[bb * NCH + t], ep);
            __syncthreads();            // all partials visible
            const int p2 = t & 31, g8 = t >> 5;      // 32 pair-slots x 8 slot-groups
            const int roff = (RC < 64) ? RC * DD : 4096;
            {
                const float* base = Gpart + (size_t)(bb * NCH + g8 * 16) * PSZ + roff + 2 * p2;
                float ax = 0.f, ay = 0.f;
                #pragma unroll
                for (int s2 = 0; s2 < 16; s2++) {
                    float2 v = ldc2(base + (size_t)s2 * PSZ);
                    ax += v.x; ay += v.y;
                }
                RED[g8 * 64 + 2 * p2]     = ax;
                RED[g8 * 64 + 2 * p2 + 1] = ay;
            }
            __syncthreads();
            if (RC < 64) {
                if (t < DD) {           // RED[512+p] = reduced G row, PERMUTED idx p
                    float u = 0.f;
                    #pragma unroll
                    for (int g = 0; g < 8; g++) u += RED[g * 64 + t];
                    RED[512 + t] = u;
                }
                __syncthreads();
                {   // T'raw[RC][c] partials; e = q4*16+e2 natural -> perm index
                    const int c = t & 63, q4 = t >> 6;
                    float u = 0.f;
                    #pragma unroll
                    for (int e2 = 0; e2 < 16; e2++) {
                        const int pidx = ((e2 & 2) << 4) + q4 * 8 + ((e2 >> 2) << 1) + (e2 & 1);
                        u += RED[512 + pidx] * B5[q4 * 16 + e2][c];
                    }
                    RED[576 + q4 * 64 + c] = u;
                }
                __syncthreads();
                if (t < 32) {
                    float v0 = 0.f, v1 = 0.f;
                    #pragma unroll
                    for (int q = 0; q < 4; q++) {
                        v0 += RED[576 + q * 64 + 2 * t];
                        v1 += RED[576 + q * 64 + 2 * t + 1];
                    }
                    stc2(&GgL[RC * DD + 2 * t], v0, v1);
                }
            } else {
                if (t < DD) {           // s final (stored natural -> natural here)
                    float u = 0.f;
                    #pragma unroll
                    for (int g = 0; g < 8; g++) u += RED[g * 64 + t];
                    RED[512 + t] = u;
                }
                __syncthreads();
                {   // su[c] partials: sum_d s[d]*Wv[d][c] over 4 d-groups
                    const int c = t & 63, q4 = t >> 6;
                    float u = 0.f;
                    #pragma unroll
                    for (int d2 = 0; d2 < 16; d2++)
                        u += RED[512 + q4 * 16 + d2] * B5[q4 * 16 + d2][c];
                    RED[576 + q4 * 64 + c] = u;
                }
                __syncthreads();
                if (t < 32) {
                    // publish s
                    stc2(&GgL[4096 + 2 * t], RED[512 + 2 * t], RED[512 + 2 * t + 1]);
                    // publish su = Wv^T s + N bv
                    float v0 = (float)NN * bvS[2 * t], v1 = (float)NN * bvS[2 * t + 1];
                    #pragma unroll
                    for (int q = 0; q < 4; q++) {
                        v0 += RED[576 + q * 64 + 2 * t];
                        v1 += RED[576 + q * 64 + 2 * t + 1];
                    }
                    stc2(&GgL[4160 + 2 * t], v0, v1);
                }
            }
            __syncthreads();            // T'/s/su stores drained
            if (t == 0) stw(&cflag[blk], ep);
        }

        // ---- stage Wb -> B4 (E done; overlaps cflag propagation) ----
        for (int i2 = t; i2 < DD * DD; i2 += NT)
            B4[i2 >> 6][i2 & 63] = Acc<T>::ld(blkw, wOff + i2);

        // ---- F: wait 65 combine flags; stage T' = T'raw + s.bv^T -> B3;
        //      load su directly ----
        {
            if (t < 65) pollw(&cflag[bb * NCH + t], ep);
            __syncthreads();            // Wb staging + T'/s/su visible
            #pragma unroll
            for (int a = 0; a < 4; a++) {
                float4 v = *(const float4*)&GgL[(r0 + a) * DD + c0];
                const float sv = GgL[4096 + r0 + a];
                v.x += sv * bvS[c0 + 0];
                v.y += sv * bvS[c0 + 1];
                v.z += sv * bvS[c0 + 2];
                v.w += sv * bvS[c0 + 3];
                *(float4*)&B3[r0 + a][c0] = v;
            }
            if (t < DD) suS[t] = GgL[4160 + t];
            __syncthreads();
        }

        // ---- H: weff = Wb + C0*(A@T' + qk su^T) -> B5 ; beff ----
        {
            float acc[4][4];
            #pragma unroll
            for (int a = 0; a < 4; a++)
                #pragma unroll
                for (int b = 0; b < 4; b++) acc[a][b] = qkS[r0 + a] * suS[c0 + b];
            #pragma unroll 2
            for (int e = 0; e < DD; e += 4)
                mm4x4(acc,
                      *(const float4*)&B2[r0 + 0][e], *(const float4*)&B2[r0 + 1][e],
                      *(const float4*)&B2[r0 + 2][e], *(const float4*)&B2[r0 + 3][e],
                      *(const float4*)&B3[e + 0][c0], *(const float4*)&B3[e + 1][c0],
                      *(const float4*)&B3[e + 2][c0], *(const float4*)&B3[e + 3][c0]);
            #pragma unroll
            for (int a = 0; a < 4; a++) {
                float4 w;
                w.x = B4[r0 + a][c0 + 0] + C0F * acc[a][0];
                w.y = B4[r0 + a][c0 + 1] + C0F * acc[a][1];
                w.z = B4[r0 + a][c0 + 2] + C0F * acc[a][2];
                w.w = B4[r0 + a][c0 + 3] + C0F * acc[a][3];
                *(float4*)&B5[r0 + a][c0] = w;      // B5 (Wv) dead after combine
            }
            {   // beff partials: kq . T' (reads B3 only)
                const int c = t & 63, q = t >> 6;
                float u = 0.f;
                #pragma unroll
                for (int e2 = 0; e2 < 16; e2++) u += kqS[q * 16 + e2] * B3[q * 16 + e2][c];
                red[q][c] = u;
            }
            __syncthreads();            // red + weff visible
            if (t < DD) beS[t] = Acc<T>::ld(blkb, bOff + t)
                               + C0F * (red[0][t] + red[1][t] + red[2][t] + red[3][t]
                                        + qbkS[0] * suS[t]);
        }
        __syncthreads();

        // ---- apply: h' = gelu(h@weff + beff) on resident rows ----
        float o[2][4];
        #pragma unroll
        for (int a = 0; a < 2; a++) {
            const int row = r + 16 * a;
            float acc2[4];
            #pragma unroll
            for (int b = 0; b < 4; b++) acc2[b] = beS[c4 + b];
            for (int d = 0; d < DD; d++) {
                float hv = sH[row][d];
                float4 w4 = *(const float4*)&B5[d][c4];
                acc2[0] += hv * w4.x; acc2[1] += hv * w4.y;
                acc2[2] += hv * w4.z; acc2[3] += hv * w4.w;
            }
            #pragma unroll
            for (int b = 0; b < 4; b++) o[a][b] = gelu_exact(acc2[b]);
        }

        if (layer == NLAYER - 1) {
            float pbv = Acc<T>::ld(pb, 0);
            #pragma unroll
            for (int a = 0; a < 2; a++) {
                float p = 0.f;
                #pragma unroll
                for (int b = 0; b < 4; b++) p += o[a][b] * Acc<T>::ld(pw, c4 + b);
                p += __shfl_xor(p, 1);
                p += __shfl_xor(p, 2);
                p += __shfl_xor(p, 4);
                p += __shfl_xor(p, 8);
                if ((t & 15) == 0) Acc<T>::st(out, row0 + r + 16 * a, p + pbv);
            }
        } else {
            __syncthreads();    // weff/beS/sH reads done before sH overwrite
            #pragma unroll
            for (int a = 0; a < 2; a++)
                *(float4*)&sH[r + 16 * a][c4] =
                    make_float4(o[a][0], o[a][1], o[a][2], o[a][3]);
            __syncthreads();
        }
    }
}

__global__ __launch_bounds__(NT) void gno_kernel(
    const void* x, const void* lw, const void* lb,
    const void* blkw, const void* blkb,
    const void* qw, const void* qb, const void* kw, const void* kb,
    const void* vw, const void* vb, const void* pw, const void* pb,
    void* out, float* Gpart, float* Gg, unsigned* bar, int mode)
{
    __shared__ alignas(16) float smem[SM_TOT];   // 99072 B
    __shared__ int stot;

    const int blk = blockIdx.x, t = threadIdx.x;

    bool isbf;
    if (mode >= 0) {
        isbf = (mode == 1);
    } else {
        // fallback: device dtype scan (same result in every block)
        if (t == 0) stot = 0;
        __syncthreads();
        int cdt = 0;
        const unsigned int* xw = (const unsigned int*)x;
        for (int i = t; i < 8192; i += NT) {
            unsigned u = xw[i] & 0xFFFFu;
            int e = (u >> 7) & 0xFF;
            cdt += (u == 0u || (e >= 100 && e <= 142)) ? 1 : 0;
        }
        atomicAdd(&stot, cdt);
        __syncthreads();
        isbf = (stot > 4915);
    }

    unsigned* aflag = bar;          // [256] producer epochs
    unsigned* cflag = bar + 256;    // [256] combine epochs (65 used per batch)

    if (isbf)
        run_net<bf16>(x, lw, lb, blkw, blkb, qw, qb, kw, kb, vw, vb, pw, pb,
                      out, Gpart, Gg, aflag, cflag, smem, blk, t);
    else
        run_net<float>(x, lw, lb, blkw, blkb, qw, qb, kw, kb, vw, vb, pw, pb,
                       out, Gpart, Gg, aflag, cflag, smem, blk, t);
}

extern "C" void kernel_launch(void* const* d_in, const int* in_sizes, int n_in,
                              void* d_out, int out_size, void* d_ws, size_t ws_size,
                              hipStream_t stream)
{
    const void* x    = d_in[0];
    const void* lw   = d_in[1];
    const void* lb   = d_in[2];
    const void* blkw = d_in[3];
    const void* blkb = d_in[4];
    const void* qw   = d_in[5];
    const void* qb   = d_in[6];
    const void* kw   = d_in[7];
    const void* kb   = d_in[8];
    const void* vw   = d_in[9];
    const void* vb   = d_in[10];
    const void* pw   = d_in[11];
    const void* pb   = d_in[12];

    // x = [2,64,64,3]: fp32 -> 98304 B, bf16 -> 49152 B
    int mode = -1;
    if (in_sizes && n_in > 0) {
        if (in_sizes[0] == 49152) mode = 1;
        else if (in_sizes[0] == 98304) mode = 0;
    }

    unsigned* bar = (unsigned*)d_ws;                      // [512] flag words
    float* Gpart  = (float*)d_ws + 512;                   // [256][4160] 4.26 MB
    float* Gg     = Gpart + (size_t)NBLK * PSZ;           // [4][2][4224] T'raw+s+su

    (void)hipMemsetAsync(bar, 0, 512 * sizeof(unsigned), stream);
    gno_kernel<<<NBLK, NT, 0, stream>>>(x, lw, lb, blkw, blkb, qw, qb, kw, kb,
                                        vw, vb, pw, pb, d_out, Gpart, Gg, bar, mode);
}

// Round 17
// 150.114 us; speedup vs baseline: 1.0244x; 1.0244x over previous
//
#include <hip/hip_runtime.h>
#include <hip/hip_bf16.h>
#include <math.h>

// GNO collapsed: h = lift(x); per layer h = gelu(h@weff + beff),
//   weff = Wb + c0*(A@T' + qk su^T),  beff = bb + c0*(kq.T' + qbk su),
//   A = Wq@Wk^T, qk = Wq@bk, kq = Wk@bq, qbk = bq.bk     (G-INDEPENDENT)
//   T' = G@Wv + s bv^T,  su = Wv^T s + N bv,  G = h^T h, s = h^T 1.
// Round 29: REVERT to r27 (150.6us bench -- session best).
// r28 lesson: E-before-D regressed (+3us): producers set aflag EARLY, so
// the combine's D-wait is short; pre-D work delays the reduce and cascades
// into every consumer's F-wait. The combine's real exclusive window is on
// its OUTPUT side (it owns reduced data before publishing), which is what
// r25 (T' in combine) and r26 (su in combine) exploited.
// Structure (r27): direct permuted G-partial stores (no LDS staging),
// combine computes T'+su, 2 rounds/layer, shadow E after D, NT=256.
// Session: 189 -> 157.3 (champion fabric) -> 154.2 -> 152.3 -> 150.6.

#define NLAYER 4
#define NB 2
#define NN 4096
#define DD 64
#define RPB 32              // rows per block (8192 rows / 256 blocks)
#define NT 256
#define NBLK 256
#define SHP 68              // padded LDS row stride (floats)
#define C0F (1.0f/32768.0f)
#define PSZ 4160            // partial floats: full G 4096 (permuted rows) + s 64
#define GSZ 4224            // published floats: T'raw 4096 + s 64 + su 64
#define NCH 128             // producers per batch

typedef __hip_bfloat16 bf16;
typedef unsigned long long u64t;

__device__ __forceinline__ float b2f(const bf16 v) { return __bfloat162float(v); }

template <typename T> struct Acc;
template <> struct Acc<float> {
    static __device__ __forceinline__ float ld(const void* p, int i) { return ((const float*)p)[i]; }
    static __device__ __forceinline__ void st(void* p, int i, float v) { ((float*)p)[i] = v; }
};
template <> struct Acc<bf16> {
    static __device__ __forceinline__ float ld(const void* p, int i) { return b2f(((const bf16*)p)[i]); }
    static __device__ __forceinline__ void st(void* p, int i, float v) { ((bf16*)p)[i] = __float2bfloat16(v); }
};

__device__ __forceinline__ float gelu_exact(float x) {
    return 0.5f * x * (1.0f + erff(x * 0.70710678118654752f));
}

// ---- device-coherent helpers (agent scope, relaxed) ----
__device__ __forceinline__ float2 ldc2(const float* p) {
    u64t v = __hip_atomic_load((const u64t*)p, __ATOMIC_RELAXED, __HIP_MEMORY_SCOPE_AGENT);
    float2 r;
    r.x = __uint_as_float((unsigned)v);
    r.y = __uint_as_float((unsigned)(v >> 32));
    return r;
}
__device__ __forceinline__ void stc(float* p, float v) {
    __hip_atomic_store((unsigned*)p, __float_as_uint(v), __ATOMIC_RELAXED, __HIP_MEMORY_SCOPE_AGENT);
}
__device__ __forceinline__ void stc2(float* p, float a, float b) {
    u64t v = ((u64t)__float_as_uint(b) << 32) | (u64t)__float_as_uint(a);
    __hip_atomic_store((u64t*)p, v, __ATOMIC_RELAXED, __HIP_MEMORY_SCOPE_AGENT);
}
__device__ __forceinline__ unsigned ldw(unsigned* p) {
    return __hip_atomic_load(p, __ATOMIC_RELAXED, __HIP_MEMORY_SCOPE_AGENT);
}
__device__ __forceinline__ void stw(unsigned* p, unsigned v) {
    __hip_atomic_store(p, v, __ATOMIC_RELAXED, __HIP_MEMORY_SCOPE_AGENT);
}
__device__ __forceinline__ void pollw(unsigned* p, unsigned ep) {
    int guard = 0;
    while (ldw(p) < ep && ++guard < (1 << 18)) __builtin_amdgcn_s_sleep(2);
}

// acc[a][b] += sum_k L[a].k * R[k].b   (NN product step)
__device__ __forceinline__ void mm4x4(float (&acc)[4][4],
    float4 L0, float4 L1, float4 L2, float4 L3,
    float4 R0, float4 R1, float4 R2, float4 R3)
{
    const float L[4][4] = {{L0.x,L0.y,L0.z,L0.w},{L1.x,L1.y,L1.z,L1.w},
                           {L2.x,L2.y,L2.z,L2.w},{L3.x,L3.y,L3.z,L3.w}};
    const float R[4][4] = {{R0.x,R0.y,R0.z,R0.w},{R1.x,R1.y,R1.z,R1.w},
                           {R2.x,R2.y,R2.z,R2.w},{R3.x,R3.y,R3.z,R3.w}};
    #pragma unroll
    for (int a = 0; a < 4; a++)
        #pragma unroll
        for (int k = 0; k < 4; k++)
            #pragma unroll
            for (int b = 0; b < 4; b++)
                acc[a][b] += L[a][k] * R[k][b];
}

// acc[a][b] += sum_k L[a].k * R[b].k   (NT product step: A = Wq @ Wk^T)
__device__ __forceinline__ void mmNT4x4(float (&acc)[4][4],
    float4 L0, float4 L1, float4 L2, float4 L3,
    float4 R0, float4 R1, float4 R2, float4 R3)
{
    const float L[4][4] = {{L0.x,L0.y,L0.z,L0.w},{L1.x,L1.y,L1.z,L1.w},
                           {L2.x,L2.y,L2.z,L2.w},{L3.x,L3.y,L3.z,L3.w}};
    const float R[4][4] = {{R0.x,R0.y,R0.z,R0.w},{R1.x,R1.y,R1.z,R1.w},
                           {R2.x,R2.y,R2.z,R2.w},{R3.x,R3.y,R3.z,R3.w}};
    #pragma unroll
    for (int a = 0; a < 4; a++)
        #pragma unroll
        for (int b = 0; b < 4; b++)
            #pragma unroll
            for (int k = 0; k < 4; k++)
                acc[a][b] += L[a][k] * R[b][k];
}

// acc[a][b] += A.a * B.b
__device__ __forceinline__ void outer4x4(float (&acc)[4][4], float4 A, float4 B)
{
    const float Aa[4] = {A.x, A.y, A.z, A.w};
    const float Ba[4] = {B.x, B.y, B.z, B.w};
    #pragma unroll
    for (int a = 0; a < 4; a++)
        #pragma unroll
        for (int b = 0; b < 4; b++)
            acc[a][b] += Aa[a] * Ba[b];
}

// LDS layout (floats):
//   sH  [32][68]  @ 0      resident h rows
//   B1  [64][68]  @ 2176   Wq
//   B2  [64][68]  @ 6528   A (shadow-computed, persists through weff)
//   B3  [64][68]  @ 10880  combine scratch RED; then T'
//   B4  [64][68]  @ 15232  Wk -> Wb
//   B5  [64][68]  @ 19584  Wv -> weff
//   smalls @ 23936..24511 ; red [4][64] @ 24512
// total 24768 floats = 99072 B -> 1 block/CU, 256 blocks co-resident.

#define SM_SS   23936
#define SM_SU   24000
#define SM_BK   24064
#define SM_BQ   24128
#define SM_BV   24192
#define SM_BE   24256
#define SM_QK   24320
#define SM_KQ   24384
#define SM_QBK  24448
#define SM_RED  24512
#define SM_TOT  24768

template <typename T>
__device__ void run_net(
    const void* x, const void* lw, const void* lb,
    const void* blkw, const void* blkb,
    const void* qw, const void* qb, const void* kw, const void* kb,
    const void* vw, const void* vb, const void* pw, const void* pb,
    void* out, float* Gpart, float* Gg,
    unsigned* aflag, unsigned* cflag,
    float* smem, int blk, int t)
{
    float (*sH)[SHP] = (float(*)[SHP])(smem);
    float (*B1)[SHP] = (float(*)[SHP])(smem + 2176);
    float (*B2)[SHP] = (float(*)[SHP])(smem + 6528);
    float (*B3)[SHP] = (float(*)[SHP])(smem + 10880);
    float (*B4)[SHP] = (float(*)[SHP])(smem + 15232);
    float (*B5)[SHP] = (float(*)[SHP])(smem + 19584);
    float* RED = smem + 10880;          // combine scratch (aliases B3)
    float* suS = smem + SM_SU;
    float* bkS = smem + SM_BK;
    float* bqS = smem + SM_BQ;
    float* bvS = smem + SM_BV;
    float* beS = smem + SM_BE;
    float* qkS = smem + SM_QK;
    float* kqS = smem + SM_KQ;
    float* qbkS = smem + SM_QBK;
    float (*red)[DD] = (float(*)[DD])(smem + SM_RED);

    const int row0 = blk * RPB;
    const int bb = blk >> 7;                      // batch of this block
    const int RC = blk & 127;                     // combine role: rows 0..63, s/su=64
    const int r = t >> 4, c4 = (t & 15) << 2;     // apply/lift mapping
    const int i4 = t >> 4, j4 = t & 15;           // 4x4 tile grid coords
    const int r0 = i4 << 2, c0 = j4 << 2;

    // ---- lift: 32 rows of h into resident LDS ----
    #pragma unroll
    for (int a = 0; a < 2; a++) {
        const int row = r + 16 * a, gr = row0 + row;
        float x0 = Acc<T>::ld(x, gr * 3 + 0);
        float x1 = Acc<T>::ld(x, gr * 3 + 1);
        float x2 = Acc<T>::ld(x, gr * 3 + 2);
        float o[4];
        #pragma unroll
        for (int b = 0; b < 4; b++) {
            int c = c4 + b;
            o[b] = Acc<T>::ld(lb, c) + x0 * Acc<T>::ld(lw, c)
                 + x1 * Acc<T>::ld(lw, DD + c) + x2 * Acc<T>::ld(lw, 2 * DD + c);
        }
        *(float4*)&sH[row][c4] = make_float4(o[0], o[1], o[2], o[3]);
    }
    __syncthreads();

    for (int layer = 0; layer < NLAYER; layer++) {
        const unsigned ep = (unsigned)(layer + 1);
        float* GgL = Gg + (size_t)(layer * NB + bb) * GSZ;   // T'raw + s + su
        const int wOff = layer * DD * DD, bOff = layer * DD;

        // ---- A: G-partial computed and stored DIRECTLY (permuted rows) ----
        // Row layout in slot: each stc2 instr covers 128B contiguous per
        // 16-lane group (col c -> permuted pair slots).
        {
            float* slot = Gpart + (size_t)blk * PSZ;
            float m[4][4];
            #pragma unroll
            for (int a = 0; a < 4; a++)
                #pragma unroll
                for (int b = 0; b < 4; b++) m[a][b] = 0.f;
            #pragma unroll 8
            for (int n = 0; n < RPB; n++)
                outer4x4(m, *(const float4*)&sH[n][r0], *(const float4*)&sH[n][c0]);
            #pragma unroll
            for (int a = 0; a < 4; a++) {
                float* rowp = slot + (r0 + a) * DD;
                stc2(rowp + 2 * j4,      m[a][0], m[a][1]);
                stc2(rowp + 32 + 2 * j4, m[a][2], m[a][3]);
            }
            if (t < DD) {
                float ss = 0.f;
                #pragma unroll 8
                for (int n = 0; n < RPB; n++) ss += sH[n][t];
                stc(&slot[4096 + t], ss);   // natural order, contiguous 4B
            }
        }
        __syncthreads();                // vmcnt(0) per wave: partial fully visible
        if (t == 0) stw(&aflag[blk], ep);

        // ---- C: stage Wq->B1, Wk->B4, Wv->B5 + bias vectors ----
        for (int i2 = t; i2 < DD * DD; i2 += NT) {
            B1[i2 >> 6][i2 & 63] = Acc<T>::ld(qw, wOff + i2);
            B4[i2 >> 6][i2 & 63] = Acc<T>::ld(kw, wOff + i2);
            B5[i2 >> 6][i2 & 63] = Acc<T>::ld(vw, wOff + i2);
        }
        if (t < DD) {
            bkS[t] = Acc<T>::ld(kb, bOff + t);
            bqS[t] = Acc<T>::ld(qb, bOff + t);
            bvS[t] = Acc<T>::ld(vb, bOff + t);
        }

        // ---- D (combine roles only): reduce row RC across 128 slots;
        //      rows 0..63 compute T'raw[RC] = G[RC]@Wv; RC==64 -> s AND su ----
        if (RC <= 64) {
            if (t < NCH) pollw(&aflag[bb * NCH + t], ep);
            __syncthreads();            // C staging + all partials visible
            const int p2 = t & 31, g8 = t >> 5;      // 32 pair-slots x 8 slot-groups
            const int roff = (RC < 64) ? RC * DD : 4096;
            {
                const float* base = Gpart + (size_t)(bb * NCH + g8 * 16) * PSZ + roff + 2 * p2;
                float ax = 0.f, ay = 0.f;
                #pragma unroll
                for (int s2 = 0; s2 < 16; s2++) {
                    float2 v = ldc2(base + (size_t)s2 * PSZ);
                    ax += v.x; ay += v.y;
                }
                RED[g8 * 64 + 2 * p2]     = ax;
                RED[g8 * 64 + 2 * p2 + 1] = ay;
            }
            __syncthreads();
            if (RC < 64) {
                if (t < DD) {           // RED[512+p] = reduced G row, PERMUTED idx p
                    float u = 0.f;
                    #pragma unroll
                    for (int g = 0; g < 8; g++) u += RED[g * 64 + t];
                    RED[512 + t] = u;
                }
                __syncthreads();
                {   // T'raw[RC][c] partials; e = q4*16+e2 natural -> perm index
                    const int c = t & 63, q4 = t >> 6;
                    float u = 0.f;
                    #pragma unroll
                    for (int e2 = 0; e2 < 16; e2++) {
                        const int pidx = ((e2 & 2) << 4) + q4 * 8 + ((e2 >> 2) << 1) + (e2 & 1);
                        u += RED[512 + pidx] * B5[q4 * 16 + e2][c];
                    }
                    RED[576 + q4 * 64 + c] = u;
                }
                __syncthreads();
                if (t < 32) {
                    float v0 = 0.f, v1 = 0.f;
                    #pragma unroll
                    for (int q = 0; q < 4; q++) {
                        v0 += RED[576 + q * 64 + 2 * t];
                        v1 += RED[576 + q * 64 + 2 * t + 1];
                    }
                    stc2(&GgL[RC * DD + 2 * t], v0, v1);
                }
            } else {
                if (t < DD) {           // s final (stored natural -> natural here)
                    float u = 0.f;
                    #pragma unroll
                    for (int g = 0; g < 8; g++) u += RED[g * 64 + t];
                    RED[512 + t] = u;
                }
                __syncthreads();
                {   // su[c] partials: sum_d s[d]*Wv[d][c] over 4 d-groups
                    const int c = t & 63, q4 = t >> 6;
                    float u = 0.f;
                    #pragma unroll
                    for (int d2 = 0; d2 < 16; d2++)
                        u += RED[512 + q4 * 16 + d2] * B5[q4 * 16 + d2][c];
                    RED[576 + q4 * 64 + c] = u;
                }
                __syncthreads();
                if (t < 32) {
                    // publish s
                    stc2(&GgL[4096 + 2 * t], RED[512 + 2 * t], RED[512 + 2 * t + 1]);
                    // publish su = Wv^T s + N bv
                    float v0 = (float)NN * bvS[2 * t], v1 = (float)NN * bvS[2 * t + 1];
                    #pragma unroll
                    for (int q = 0; q < 4; q++) {
                        v0 += RED[576 + q * 64 + 2 * t];
                        v1 += RED[576 + q * 64 + 2 * t + 1];
                    }
                    stc2(&GgL[4160 + 2 * t], v0, v1);
                }
            }
            __syncthreads();            // T'/s/su stores drained
            if (t == 0) stw(&cflag[blk], ep);
        }
        __syncthreads();                // C staging visible for non-combine blocks

        // ---- E: A = Wq@Wk^T (shadow), qk, kq, qbk ----
        {
            float acc[4][4];
            #pragma unroll
            for (int a = 0; a < 4; a++)
                #pragma unroll
                for (int b = 0; b < 4; b++) acc[a][b] = 0.f;
            #pragma unroll 2
            for (int e = 0; e < DD; e += 4)
                mmNT4x4(acc,
                      *(const float4*)&B1[r0 + 0][e], *(const float4*)&B1[r0 + 1][e],
                      *(const float4*)&B1[r0 + 2][e], *(const float4*)&B1[r0 + 3][e],
                      *(const float4*)&B4[c0 + 0][e], *(const float4*)&B4[c0 + 1][e],
                      *(const float4*)&B4[c0 + 2][e], *(const float4*)&B4[c0 + 3][e]);
            #pragma unroll
            for (int a = 0; a < 4; a++)
                *(float4*)&B2[r0 + a][c0] = make_float4(acc[a][0], acc[a][1], acc[a][2], acc[a][3]);

            if (t < DD) {               // qk = Wq@bk
                float u = 0.f;
                for (int e = 0; e < DD; e++) u += B1[t][e] * bkS[e];
                qkS[t] = u;
            } else if (t < 2 * DD) {    // kq = Wk@bq
                const int rr = t - DD;
                float u = 0.f;
                for (int e = 0; e < DD; e++) u += B4[rr][e] * bqS[e];
                kqS[rr] = u;
            } else if (t == 2 * DD) {   // qbk = bq.bk
                float u = 0.f;
                for (int e = 0; e < DD; e++) u += bqS[e] * bkS[e];
                qbkS[0] = u;
            }
        }
        __syncthreads();                // B4 (Wk) free; B1 free
        for (int i2 = t; i2 < DD * DD; i2 += NT)
            B4[i2 >> 6][i2 & 63] = Acc<T>::ld(blkw, wOff + i2);   // Wb

        // ---- F: wait 65 combine flags; stage T' = T'raw + s.bv^T -> B3;
        //      load su directly (su phase deleted) ----
        {
            if (t < 65) pollw(&cflag[bb * NCH + t], ep);
            __syncthreads();            // Wb staging + T'/s/su visible
            #pragma unroll
            for (int a = 0; a < 4; a++) {
                float4 v = *(const float4*)&GgL[(r0 + a) * DD + c0];
                const float sv = GgL[4096 + r0 + a];
                v.x += sv * bvS[c0 + 0];
                v.y += sv * bvS[c0 + 1];
                v.z += sv * bvS[c0 + 2];
                v.w += sv * bvS[c0 + 3];
                *(float4*)&B3[r0 + a][c0] = v;
            }
            if (t < DD) suS[t] = GgL[4160 + t];
            __syncthreads();
        }

        // ---- H: weff = Wb + C0*(A@T' + qk su^T) -> B5 ; beff ----
        {
            float acc[4][4];
            #pragma unroll
            for (int a = 0; a < 4; a++)
                #pragma unroll
                for (int b = 0; b < 4; b++) acc[a][b] = qkS[r0 + a] * suS[c0 + b];
            #pragma unroll 2
            for (int e = 0; e < DD; e += 4)
                mm4x4(acc,
                      *(const float4*)&B2[r0 + 0][e], *(const float4*)&B2[r0 + 1][e],
                      *(const float4*)&B2[r0 + 2][e], *(const float4*)&B2[r0 + 3][e],
                      *(const float4*)&B3[e + 0][c0], *(const float4*)&B3[e + 1][c0],
                      *(const float4*)&B3[e + 2][c0], *(const float4*)&B3[e + 3][c0]);
            #pragma unroll
            for (int a = 0; a < 4; a++) {
                float4 w;
                w.x = B4[r0 + a][c0 + 0] + C0F * acc[a][0];
                w.y = B4[r0 + a][c0 + 1] + C0F * acc[a][1];
                w.z = B4[r0 + a][c0 + 2] + C0F * acc[a][2];
                w.w = B4[r0 + a][c0 + 3] + C0F * acc[a][3];
                *(float4*)&B5[r0 + a][c0] = w;      // B5 (Wv) dead after combine
            }
            {   // beff partials: kq . T' (reads B3 only)
                const int c = t & 63, q = t >> 6;
                float u = 0.f;
                #pragma unroll
                for (int e2 = 0; e2 < 16; e2++) u += kqS[q * 16 + e2] * B3[q * 16 + e2][c];
                red[q][c] = u;
            }
            __syncthreads();            // red + weff visible
            if (t < DD) beS[t] = Acc<T>::ld(blkb, bOff + t)
                               + C0F * (red[0][t] + red[1][t] + red[2][t] + red[3][t]
                                        + qbkS[0] * suS[t]);
        }
        __syncthreads();

        // ---- apply: h' = gelu(h@weff + beff) on resident rows ----
        float o[2][4];
        #pragma unroll
        for (int a = 0; a < 2; a++) {
            const int row = r + 16 * a;
            float acc2[4];
            #pragma unroll
            for (int b = 0; b < 4; b++) acc2[b] = beS[c4 + b];
            for (int d = 0; d < DD; d++) {
                float hv = sH[row][d];
                float4 w4 = *(const float4*)&B5[d][c4];
                acc2[0] += hv * w4.x; acc2[1] += hv * w4.y;
                acc2[2] += hv * w4.z; acc2[3] += hv * w4.w;
            }
            #pragma unroll
            for (int b = 0; b < 4; b++) o[a][b] = gelu_exact(acc2[b]);
        }

        if (layer == NLAYER - 1) {
            float pbv = Acc<T>::ld(pb, 0);
            #pragma unroll
            for (int a = 0; a < 2; a++) {
                float p = 0.f;
                #pragma unroll
                for (int b = 0; b < 4; b++) p += o[a][b] * Acc<T>::ld(pw, c4 + b);
                p += __shfl_xor(p, 1);
                p += __shfl_xor(p, 2);
                p += __shfl_xor(p, 4);
                p += __shfl_xor(p, 8);
                if ((t & 15) == 0) Acc<T>::st(out, row0 + r + 16 * a, p + pbv);
            }
        } else {
            __syncthreads();    // weff/beS/sH reads done before sH overwrite
            #pragma unroll
            for (int a = 0; a < 2; a++)
                *(float4*)&sH[r + 16 * a][c4] =
                    make_float4(o[a][0], o[a][1], o[a][2], o[a][3]);
            __syncthreads();
        }
    }
}

__global__ __launch_bounds__(NT) void gno_kernel(
    const void* x, const void* lw, const void* lb,
    const void* blkw, const void* blkb,
    const void* qw, const void* qb, const void* kw, const void* kb,
    const void* vw, const void* vb, const void* pw, const void* pb,
    void* out, float* Gpart, float* Gg, unsigned* bar, int mode)
{
    __shared__ alignas(16) float smem[SM_TOT];   // 99072 B
    __shared__ int stot;

    const int blk = blockIdx.x, t = threadIdx.x;

    bool isbf;
    if (mode >= 0) {
        isbf = (mode == 1);
    } else {
        // fallback: device dtype scan (same result in every block)
        if (t == 0) stot = 0;
        __syncthreads();
        int cdt = 0;
        const unsigned int* xw = (const unsigned int*)x;
        for (int i = t; i < 8192; i += NT) {
            unsigned u = xw[i] & 0xFFFFu;
            int e = (u >> 7) & 0xFF;
            cdt += (u == 0u || (e >= 100 && e <= 142)) ? 1 : 0;
        }
        atomicAdd(&stot, cdt);
        __syncthreads();
        isbf = (stot > 4915);
    }

    unsigned* aflag = bar;          // [256] producer epochs
    unsigned* cflag = bar + 256;    // [256] combine epochs (65 used per batch)

    if (isbf)
        run_net<bf16>(x, lw, lb, blkw, blkb, qw, qb, kw, kb, vw, vb, pw, pb,
                      out, Gpart, Gg, aflag, cflag, smem, blk, t);
    else
        run_net<float>(x, lw, lb, blkw, blkb, qw, qb, kw, kb, vw, vb, pw, pb,
                       out, Gpart, Gg, aflag, cflag, smem, blk, t);
}

extern "C" void kernel_launch(void* const* d_in, const int* in_sizes, int n_in,
                              void* d_out, int out_size, void* d_ws, size_t ws_size,
                              hipStream_t stream)
{
    const void* x    = d_in[0];
    const void* lw   = d_in[1];
    const void* lb   = d_in[2];
    const void* blkw = d_in[3];
    const void* blkb = d_in[4];
    const void* qw   = d_in[5];
    const void* qb   = d_in[6];
    const void* kw   = d_in[7];
    const void* kb   = d_in[8];
    const void* vw   = d_in[9];
    const void* vb   = d_in[10];
    const void* pw   = d_in[11];
    const void* pb   = d_in[12];

    // x = [2,64,64,3]: fp32 -> 98304 B, bf16 -> 49152 B
    int mode = -1;
    if (in_sizes && n_in > 0) {
        if (in_sizes[0] == 49152) mode = 1;
        else if (in_sizes[0] == 98304) mode = 0;
    }

    unsigned* bar = (unsigned*)d_ws;                      // [512] flag words
    float* Gpart  = (float*)d_ws + 512;                   // [256][4160] 4.26 MB
    float* Gg     = Gpart + (size_t)NBLK * PSZ;           // [4][2][4224] T'raw+s+su

    (void)hipMemsetAsync(bar, 0, 512 * sizeof(unsigned), stream);
    gno_kernel<<<NBLK, NT, 0, stream>>>(x, lw, lb, blkw, blkb, qw, qb, kw, kb,
                                        vw, vb, pw, pb, d_out, Gpart, Gg, bar, mode);
}